// Round 9
// baseline (75285.400 us; speedup 1.0000x reference)
//
#include <hip/hip_runtime.h>

// ---------------------------------------------------------------------------
// FarGAN wave head. R8: ZERO inter-block synchronization.
//   Sequence chunked (40 x 200 steps). Per chunk, 5 stream-ordered launches:
//     k_rec<0> -> k_gemm(wih1) -> k_rec<1> -> k_gemm(wih2) -> k_rec<2>
//   The stream IS the barrier. No atomics, no flags, no spin loops, no
//   coherent (sc0/sc1) traffic. All buffers plain cached loads/stores.
//   Recurrence closes in LDS inside one block; weights as MFMA B-frags.
// ---------------------------------------------------------------------------

#define B_ 16
#define S_ 8000
#define C_ 200         // chunk steps
#define NC_ 40         // chunks
#define GRUIN_ 194
#define TWO_PI_F 6.2831853071795864769f

// ws offsets (bytes)
#define OFF_DV     0         // 800 f32
#define OFF_V      4096      // 800 f32
#define OFF_SIN    8192      // 8000*16 f32
#define OFF_COS    520192
#define OFF_PE     1032192   // 16*50*64 f32
#define OFF_COND   1236992   // 16*200*128 f32
#define OFF_XF     2875392   // 200*3072 bf16 (cond|pe A-frags)
#define OFF_WF     4104192   // 6*216*512 bf16 (B-frags)
#define OFF_HSEQ   5431296   // 200*768 u64 (h frag image, chunk-local)
#define OFF_GI     6660096   // 200*2304 u64 (f16 gi, chunk-local)
#define OFF_STB    10346496  // 3*768 u64  (bf16 h image state)
#define OFF_STF    10364928  // 3*768 f32x4 (f32 gate-state)
#define OFF_SAMPLE 10401792  // 16*8000 f32
// end 10,913,792 B

typedef short s16x8 __attribute__((ext_vector_type(8)));
typedef float f32x4 __attribute__((ext_vector_type(4)));
typedef unsigned long long u64;

__device__ __forceinline__ short f2bf(float f) {
  unsigned u = __float_as_uint(f);
  return (short)((u + 0x7FFFu + ((u >> 16) & 1u)) >> 16);
}
__device__ __forceinline__ float sigm(float x) {
  return __fdividef(1.f, 1.f + __expf(-x));
}
__device__ __forceinline__ float tanhx(float x) {
  float e = __expf(2.f * x);
  return __fdividef(e - 1.f, e + 1.f);
}
#define BAR() asm volatile("s_waitcnt lgkmcnt(0)\n\ts_barrier" ::: "memory")

// ---------------------------------------------------------------------------
__global__ void k_frame(const float* __restrict__ feats,
                        const float* __restrict__ pembed,
                        const float* __restrict__ w1, const float* __restrict__ b1,
                        const float* __restrict__ w2, const float* __restrict__ b2,
                        char* ws) {
  const int bt = blockIdx.x, tid = threadIdx.x;   // 128 thr
  float* dvp = (float*)(ws + OFF_DV);
  float* vp  = (float*)(ws + OFF_V);
  float* pep = (float*)(ws + OFF_PE);
  float* cnd = (float*)(ws + OFF_COND);
  __shared__ float fin[112];
  __shared__ float h1[256];
  __shared__ int   sidx;
  if (tid == 0) {
    float f0 = feats[bt * 48 + 46], vo = feats[bt * 48 + 47];
    float period = fminf(fmaxf(256.f * exp2f(-(f0 + 2.f)), 32.f), 255.f);
    int idx = (int)rintf(period) - 32;
    float f0hz = 16000.f / fmaxf(period, 1.f);
    float v = fminf(fmaxf(vo, 0.f), 1.f);
    float delta = TWO_PI_F * fmaxf(f0hz, 60.f) * (1.f / 16000.f);
    dvp[bt] = delta * v; vp[bt] = v; sidx = idx;
  }
  __syncthreads();
  if (tid < 48) fin[tid] = feats[bt * 48 + tid];
  if (tid < 64) { float pv = pembed[sidx * 64 + tid]; fin[48 + tid] = pv; pep[bt * 64 + tid] = pv; }
  __syncthreads();
  #pragma unroll
  for (int rr = 0; rr < 2; ++rr) {
    int r = tid + rr * 128;
    const float* wr = w1 + r * 112;
    float acc = b1[r];
    #pragma unroll 4
    for (int k = 0; k < 112; ++k) acc += wr[k] * fin[k];
    h1[r] = 0.5f * acc * (1.f + erff(acc * 0.70710678118654752440f));
  }
  __syncthreads();
  const int b = bt / 50, t = bt - b * 50;
  #pragma unroll
  for (int rr = 0; rr < 4; ++rr) {
    int r = tid + rr * 128;
    const float* wr = w2 + r * 256;
    float acc = b2[r];
    #pragma unroll 4
    for (int k = 0; k < 256; ++k) acc += wr[k] * h1[k];
    int sf = r >> 7, c = r & 127;
    cnd[((b * 200) + (t * 4 + sf)) * 128 + c] = acc;
  }
}

// ---------------------------------------------------------------------------
__global__ void k_phase(char* ws) {
  const int b = blockIdx.x, tid = threadIdx.x;    // 256 thr
  const float* dvp = (const float*)(ws + OFF_DV);
  float* sinA = (float*)(ws + OFF_SIN);
  float* cosA = (float*)(ws + OFF_COS);
  __shared__ float ps[200], dvs[200];
  if (tid == 0) {
    float c = 0.f;
    for (int ts = 0; ts < 200; ++ts) {
      float d = dvp[b * 50 + (ts >> 2)];
      dvs[ts] = d;
      float inc = d * 40.f;
      c = c + inc;
      ps[ts] = fmodf(c - inc, TWO_PI_F);
    }
  }
  __syncthreads();
  for (int i = tid; i < S_; i += 256) {
    int ts = i / 40, k = i - ts * 40;
    float ph = ps[ts] + dvs[ts] * (float)k;
    sinA[(size_t)i * 16 + b] = sinf(ph);
    cosA[(size_t)i * 16 + b] = cosf(ph);
  }
}

// ---------------------------------------------------------------------------
// pack [cond(128)|pe(64)] per ts into bf16 A-frags
__global__ void k_xpack(char* ws) {
  const int ts = blockIdx.x, tid = threadIdx.x;   // 200 blocks, 256 thr
  const int t = ts >> 2;
  const float* cnd = (const float*)(ws + OFF_COND);
  const float* pep = (const float*)(ws + OFF_PE);
  short* xf = (short*)(ws + OFF_XF) + (size_t)ts * 3072;
  for (int i = tid; i < 3072; i += 256) {
    int kt = i >> 9, r = i & 511, lane = r >> 3, e = r & 7;
    int k = kt * 32 + 16 * (e >> 2) + 4 * (lane >> 4) + (e & 3);
    int b = lane & 15;
    float v = (k < 128) ? cnd[((b * 200) + ts) * 128 + k]
                        : pep[(b * 50 + t) * 64 + (k - 128)];
    xf[i] = f2bf(v);
  }
}

// ---------------------------------------------------------------------------
// pack 6 matrices: 0=whh0 1=whh1 2=whh2 3=wih1 4=wih2 5=wih0[:, :192]
__global__ void k_wprep(const float* __restrict__ whh0, const float* __restrict__ whh1,
                        const float* __restrict__ whh2, const float* __restrict__ wih1,
                        const float* __restrict__ wih2, const float* __restrict__ wih0,
                        char* ws) {
  const int blk = blockIdx.x;           // 1296 blocks, 64 thr
  const int mat = blk / 216, rem = blk - mat * 216;
  const int nt = rem / 6, kt = rem - nt * 6;
  const int lane = threadIdx.x;
  const float* W; int stride;
  if (mat == 0)      { W = whh0; stride = 192; }
  else if (mat == 1) { W = whh1; stride = 192; }
  else if (mat == 2) { W = whh2; stride = 192; }
  else if (mat == 3) { W = wih1; stride = 192; }
  else if (mat == 4) { W = wih2; stride = 192; }
  else               { W = wih0; stride = 194; }
  short* dst = (short*)(ws + OFF_WF) + ((size_t)(mat * 216) + nt * 6 + kt) * 512 + lane * 8;
  const int row = nt * 16 + (lane & 15);
  const int g = lane >> 4;
  #pragma unroll
  for (int e = 0; e < 8; ++e) {
    int k = kt * 32 + 16 * (e >> 2) + 4 * g + (e & 3);
    dst[e] = f2bf(W[(size_t)row * stride + k]);
  }
}

// ---------------------------------------------------------------------------
// k_rec<L>: ONE block, 768 thr (12 waves), C_ steps of layer L.
//   h recurrence in LDS; gi from chunk buffer (plain loads, 4-step prefetch);
//   publishes h frag-image to hseq (L<2) or sample partials (L==2).
// ---------------------------------------------------------------------------
template<int L>
__global__ __launch_bounds__(768, 1)
void k_rec(const int c0,
           const short* __restrict__ wf, const short* __restrict__ xfb,
           const float* __restrict__ sinA, const float* __restrict__ cosA,
           const u64* __restrict__ gi, u64* __restrict__ hseq,
           u64* __restrict__ stb, f32x4* __restrict__ stf,
           float* __restrict__ sample,
           const float* __restrict__ wih0, const float* __restrict__ bih0,
           const float* __restrict__ bhh, const float* __restrict__ outw) {
  const int tid = threadIdx.x;
  const int ut = tid >> 6, lane = tid & 63, lg = lane >> 4, l15 = lane & 15;
  const int rdoff = (lane ^ ((lane >> 4) & 3)) * 8;

  __shared__ __align__(16) short hbuf[2 * 3072];
  __shared__ float plds[2 * 12 * 16];

  // weights (18 B-frags / thread)
  s16x8 WH[3][6];
  float bh[3];
  #pragma unroll
  for (int g = 0; g < 3; ++g) {
    const int nt = g * 12 + ut;
    #pragma unroll
    for (int kt = 0; kt < 6; ++kt)
      WH[g][kt] = *(const s16x8*)(wf + ((size_t)(L * 216) + nt * 6 + kt) * 512 + lane * 8);
    bh[g] = bhh[g * 192 + 16 * ut + l15];
  }
  float wsn[3], wcs[3], bi0[3];
  if constexpr (L == 0) {
    #pragma unroll
    for (int g = 0; g < 3; ++g) {
      int row = g * 192 + 16 * ut + l15;
      wsn[g] = wih0[(size_t)row * GRUIN_ + 192];
      wcs[g] = wih0[(size_t)row * GRUIN_ + 193];
      bi0[g] = bih0[row];
    }
  }
  float ow = 0.f;
  if constexpr (L == 2) ow = outw[16 * ut + l15];

  // state (exact f32 continuity across chunks)
  f32x4 h = {0.f, 0.f, 0.f, 0.f};
  if (c0 == 0) {
    ((u64*)hbuf)[tid] = 0;
    ((u64*)hbuf)[768 + tid] = 0;
  } else {
    ((u64*)hbuf)[tid] = stb[L * 768 + tid];   // h image -> hbuf[0]
    ((u64*)hbuf)[768 + tid] = 0;
    h = stf[L * 768 + tid];
  }
  __syncthreads();

  f32x4 gbf[3];
  u64 gcur[4][3], gnx[4][3];
  const int kt_w = ut >> 1;
  const int e_ = ((ut & 1) << 2) | (l15 & 3);
  const int q_ = l15 >> 2;

  for (int u = 0; u < C_; u += 4) {
    // ---- gi: rotate + issue next group's loads (plain, cached) ----
    if constexpr (L > 0) {
      if (u == 0) {
        #pragma unroll
        for (int s = 0; s < 4; ++s)
          #pragma unroll
          for (int g = 0; g < 3; ++g)
            gcur[s][g] = gi[(size_t)s * 2304 + (12 * g + ut) * 64 + lane];
      } else {
        #pragma unroll
        for (int s = 0; s < 4; ++s)
          #pragma unroll
          for (int g = 0; g < 3; ++g)
            gcur[s][g] = gnx[s][g];
      }
      #pragma unroll
      for (int s = 0; s < 4; ++s) {
        int un = u + 4 + s; if (un > C_ - 1) un = C_ - 1;
        #pragma unroll
        for (int g = 0; g < 3; ++g)
          gnx[s][g] = gi[(size_t)un * 2304 + (12 * g + ut) * 64 + lane];
      }
    }
    // ---- gbase GEMM every 40 steps (layer 0) ----
    if constexpr (L == 0) {
      if ((c0 + u) % 40 == 0) {
        const int ts = (c0 + u) / 40;
        const short* xp = xfb + (size_t)ts * 3072;
        s16x8 xfr[6];
        #pragma unroll
        for (int kt = 0; kt < 6; ++kt) xfr[kt] = *(const s16x8*)(xp + kt * 512 + lane * 8);
        #pragma unroll
        for (int g = 0; g < 3; ++g) {
          f32x4 a = {bi0[g], bi0[g], bi0[g], bi0[g]};
          #pragma unroll
          for (int kt = 0; kt < 6; ++kt) {
            s16x8 wfr = *(const s16x8*)(wf + ((size_t)(5 * 216) + (g * 12 + ut) * 6 + kt) * 512 + lane * 8);
            a = __builtin_amdgcn_mfma_f32_16x16x32_bf16(xfr[kt], wfr, a, 0, 0, 0);
          }
          gbf[g] = a;
        }
      }
    }
    // ---- 4 substeps ----
    #pragma unroll
    for (int s = 0; s < 4; ++s) {
      const int us = u + s;
      const int t = c0 + us;
      // deferred sample store (L2)
      if constexpr (L == 2) {
        if (us > 0 && tid < 16) {
          float sm = 0.f;
          #pragma unroll
          for (int uu = 0; uu < 12; ++uu) sm += plds[(((us - 1) & 1) * 12 + uu) * 16 + tid];
          sample[(size_t)tid * S_ + (t - 1)] = sm;
        }
      }
      f32x4 s4, c4;
      if constexpr (L == 0) {
        s4 = *(const f32x4*)(sinA + (size_t)t * 16 + lg * 4);
        c4 = *(const f32x4*)(cosA + (size_t)t * 16 + lg * 4);
      }
      // LDS -> A-frags
      s16x8 hf[6];
      #pragma unroll
      for (int kt = 0; kt < 6; ++kt)
        hf[kt] = *(const s16x8*)(hbuf + (us & 1) * 3072 + kt * 512 + rdoff);
      // 18 MFMA
      f32x4 acc0 = {bh[0], bh[0], bh[0], bh[0]};
      f32x4 acc1 = {bh[1], bh[1], bh[1], bh[1]};
      f32x4 acc2 = {bh[2], bh[2], bh[2], bh[2]};
      #pragma unroll
      for (int kt = 0; kt < 6; ++kt) {
        acc0 = __builtin_amdgcn_mfma_f32_16x16x32_bf16(hf[kt], WH[0][kt], acc0, 0, 0, 0);
        acc1 = __builtin_amdgcn_mfma_f32_16x16x32_bf16(hf[kt], WH[1][kt], acc1, 0, 0, 0);
        acc2 = __builtin_amdgcn_mfma_f32_16x16x32_bf16(hf[kt], WH[2][kt], acc2, 0, 0, 0);
      }
      // gates
      f32x4 gr, gz, gn;
      if constexpr (L == 0) {
        gr = gbf[0] + s4 * wsn[0] + c4 * wcs[0];
        gz = gbf[1] + s4 * wsn[1] + c4 * wcs[1];
        gn = gbf[2] + s4 * wsn[2] + c4 * wcs[2];
      } else {
        union { u64 u; _Float16 hh[4]; } u0, u1, u2;
        u0.u = gcur[s][0]; u1.u = gcur[s][1]; u2.u = gcur[s][2];
        #pragma unroll
        for (int j = 0; j < 4; ++j) { gr[j] = (float)u0.hh[j]; gz[j] = (float)u1.hh[j]; gn[j] = (float)u2.hh[j]; }
      }
      #pragma unroll
      for (int j = 0; j < 4; ++j) {
        float r = sigm(gr[j] + acc0[j]);
        float z = sigm(gz[j] + acc1[j]);
        float n = tanhx(gn[j] + r * acc2[j]);
        h[j] = n + z * (h[j] - n);
      }
      // write h' -> swizzled A-frag LDS (other buffer)
      {
        short* wb = hbuf + ((us & 1) ^ 1) * 3072 + kt_w * 512;
        #pragma unroll
        for (int j = 0; j < 4; ++j) {
          int b16 = ((4 * lg + j) | (q_ << 4)) ^ q_;
          wb[b16 * 8 + e_] = f2bf(h[j]);
        }
      }
      // head partials (L2)
      if constexpr (L == 2) {
        #pragma unroll
        for (int j = 0; j < 4; ++j) {
          float p = ow * h[j];
          p += __shfl_xor(p, 1); p += __shfl_xor(p, 2);
          p += __shfl_xor(p, 4); p += __shfl_xor(p, 8);
          if (l15 == 0) plds[((us & 1) * 12 + ut) * 16 + lg * 4 + j] = p;
        }
      }
      BAR();
      // publish completed h'[us] frag image (plain store, drains at kernel end)
      if constexpr (L < 2) {
        hseq[(size_t)us * 768 + tid] = ((const u64*)hbuf)[(((us & 1) ^ 1)) * 768 + tid];
      }
    }
  }
  // tail: flush last sample (L2), persist state
  if constexpr (L == 2) {
    if (tid < 16) {
      float sm = 0.f;
      #pragma unroll
      for (int uu = 0; uu < 12; ++uu) sm += plds[(((C_ - 1) & 1) * 12 + uu) * 16 + tid];
      sample[(size_t)tid * S_ + (c0 + C_ - 1)] = sm;
    }
  }
  stb[L * 768 + tid] = ((const u64*)hbuf)[tid];   // C_ even -> final image in hbuf[0]
  stf[L * 768 + tid] = h;
}

// ---------------------------------------------------------------------------
// k_gemm: gi[u] = bih + Wih @ h[u] for one chunk. C_/8 blocks x 768 thr.
// Fully parallel, no recurrence, plain cached memory.
// ---------------------------------------------------------------------------
__global__ __launch_bounds__(768, 1)
void k_gemm(const short* __restrict__ wf, const int mat,
            const u64* __restrict__ hseq, u64* __restrict__ gi,
            const float* __restrict__ bih) {
  const int blk = blockIdx.x;
  const int tid = threadIdx.x;
  const int ut = tid >> 6, lane = tid & 63, l15 = lane & 15;
  const int rdoff = (lane ^ ((lane >> 4) & 3)) * 8;
  __shared__ __align__(16) u64 hst[8 * 768];

  s16x8 WB[3][6];
  float bi[3];
  #pragma unroll
  for (int g = 0; g < 3; ++g) {
    const int nt = g * 12 + ut;
    #pragma unroll
    for (int kt = 0; kt < 6; ++kt)
      WB[g][kt] = *(const s16x8*)(wf + ((size_t)(mat * 216) + nt * 6 + kt) * 512 + lane * 8);
    bi[g] = bih[g * 192 + 16 * ut + l15];
  }

  const int u0 = blk * 8;
  #pragma unroll
  for (int s = 0; s < 8; ++s)
    hst[s * 768 + tid] = hseq[(size_t)(u0 + s) * 768 + tid];
  __syncthreads();

  #pragma unroll
  for (int s = 0; s < 8; ++s) {
    const short* hp = (const short*)(hst + s * 768);
    s16x8 hf[6];
    #pragma unroll
    for (int kt = 0; kt < 6; ++kt)
      hf[kt] = *(const s16x8*)(hp + kt * 512 + rdoff);
    u64* dr = gi + (size_t)(u0 + s) * 2304 + lane;
    #pragma unroll
    for (int g = 0; g < 3; ++g) {
      f32x4 a = {bi[g], bi[g], bi[g], bi[g]};
      #pragma unroll
      for (int kt = 0; kt < 6; ++kt)
        a = __builtin_amdgcn_mfma_f32_16x16x32_bf16(hf[kt], WB[g][kt], a, 0, 0, 0);
      union { _Float16 hh[4]; u64 u; } pk;
      #pragma unroll
      for (int j = 0; j < 4; ++j) pk.hh[j] = (_Float16)a[j];
      dr[(12 * g + ut) * 64] = pk.u;
    }
  }
}

// ---------------------------------------------------------------------------
__global__ void k_final(char* ws, const float* __restrict__ noise,
                        const float* __restrict__ outb, const float* __restrict__ lgain,
                        float* __restrict__ out) {
  int i = blockIdx.x * 256 + threadIdx.x;
  if (i >= B_ * S_) return;
  int b = i / S_, s = i - b * S_;
  const float* sample = (const float*)(ws + OFF_SAMPLE);
  const float* vp     = (const float*)(ws + OFF_V);
  float smp = sample[(size_t)b * S_ + s] + outb[0];
  float v = vp[b * 50 + s / 160];
  float noisy = 0.6f * smp + 0.4f * (noise[(size_t)b * S_ + s] * 0.003f);
  float sm2 = v * smp + (1.f - v) * noisy;
  float wave = fminf(fmaxf(sm2, -1.f), 1.f);
  float gain = fminf(fmaxf(expf(lgain[0]), 0.5f), 1.5f);
  out[i] = 1.1f * tanhf(0.9f * gain * wave);
}

// ---------------------------------------------------------------------------
extern "C" void kernel_launch(void* const* d_in, const int* in_sizes, int n_in,
                              void* d_out, int out_size, void* d_ws, size_t ws_size,
                              hipStream_t stream) {
  (void)in_sizes; (void)n_in; (void)out_size; (void)ws_size;
  const float* feats  = (const float*)d_in[0];
  const float* noise  = (const float*)d_in[1];
  const float* pembed = (const float*)d_in[2];
  const float* fpw1   = (const float*)d_in[3];
  const float* fpb1   = (const float*)d_in[4];
  const float* fpw2   = (const float*)d_in[5];
  const float* fpb2   = (const float*)d_in[6];
  const float* outw   = (const float*)d_in[7];
  const float* outb   = (const float*)d_in[8];
  const float* lgain  = (const float*)d_in[9];
  const float* wih0   = (const float*)d_in[10];
  const float* whh0   = (const float*)d_in[11];
  const float* bih0   = (const float*)d_in[12];
  const float* bhh0   = (const float*)d_in[13];
  const float* wih1   = (const float*)d_in[14];
  const float* whh1   = (const float*)d_in[15];
  const float* bih1   = (const float*)d_in[16];
  const float* bhh1   = (const float*)d_in[17];
  const float* wih2   = (const float*)d_in[18];
  const float* whh2   = (const float*)d_in[19];
  const float* bih2   = (const float*)d_in[20];
  const float* bhh2   = (const float*)d_in[21];
  char* ws = (char*)d_ws;
  float* out = (float*)d_out;

  const short* wfp  = (const short*)(ws + OFF_WF);
  const short* xfp  = (const short*)(ws + OFF_XF);
  const float* sinp = (const float*)(ws + OFF_SIN);
  const float* cosp = (const float*)(ws + OFF_COS);
  u64*   hseq = (u64*)(ws + OFF_HSEQ);
  u64*   gip  = (u64*)(ws + OFF_GI);
  u64*   stb  = (u64*)(ws + OFF_STB);
  f32x4* stf  = (f32x4*)(ws + OFF_STF);
  float* smp  = (float*)(ws + OFF_SAMPLE);

  k_wprep<<<dim3(1296), dim3(64), 0, stream>>>(whh0, whh1, whh2, wih1, wih2, wih0, ws);
  k_frame<<<dim3(B_ * 50), dim3(128), 0, stream>>>(feats, pembed, fpw1, fpb1, fpw2, fpb2, ws);
  k_phase<<<dim3(B_), dim3(256), 0, stream>>>(ws);
  k_xpack<<<dim3(200), dim3(256), 0, stream>>>(ws);

  for (int c = 0; c < NC_; ++c) {
    const int c0 = c * C_;
    k_rec<0><<<dim3(1), dim3(768), 0, stream>>>(c0, wfp, xfp, sinp, cosp,
        gip, hseq, stb, stf, smp, wih0, bih0, bhh0, outw);
    k_gemm<<<dim3(C_ / 8), dim3(768), 0, stream>>>(wfp, 3, hseq, gip, bih1);
    k_rec<1><<<dim3(1), dim3(768), 0, stream>>>(c0, wfp, xfp, sinp, cosp,
        gip, hseq, stb, stf, smp, wih0, bih0, bhh1, outw);
    k_gemm<<<dim3(C_ / 8), dim3(768), 0, stream>>>(wfp, 4, hseq, gip, bih2);
    k_rec<2><<<dim3(1), dim3(768), 0, stream>>>(c0, wfp, xfp, sinp, cosp,
        gip, hseq, stb, stf, smp, wih0, bih0, bhh2, outw);
  }

  k_final<<<dim3((B_ * S_ + 255) / 256), dim3(256), 0, stream>>>(ws, noise, outb, lgain, out);
}